// Round 13
// baseline (73.655 us; speedup 1.0000x reference)
//
#include <hip/hip_runtime.h>
#include <hip/hip_bf16.h>

#define BATCH 8
#define SEQ   2048
#define DMS   1024
#define KSZ   128
#define OD    1152   // 1024 + 128

typedef unsigned short u16;
typedef unsigned int   u32;
typedef __attribute__((ext_vector_type(4)))  float  f32x4;
typedef __attribute__((ext_vector_type(16))) float  f32x16;
typedef __attribute__((ext_vector_type(8)))  __bf16 bf16x8;

union U128 { uint4 u4; bf16x8 b8; u16 us[8]; u32 u[4]; };

__device__ inline u16 f2bf(float f) {
  union { __bf16 h; u16 u; } c;
  c.h = (__bf16)f;
  return c.u;
}

__device__ inline u32 packbf2(float a, float b) {
  return (u32)f2bf(a) | ((u32)f2bf(b) << 16);
}

__device__ inline float fexp2(float x) {
  float r;
  asm("v_exp_f32 %0, %1" : "=v"(r) : "v"(x));
  return r;
}

__device__ inline f32x16 mfma32(bf16x8 a, bf16x8 b, f32x16 c) {
  return __builtin_amdgcn_mfma_f32_32x32x16_bf16(a, b, c, 0, 0, 0);
}

__device__ inline uint4 pack8bf(float4 a, float4 b) {
  U128 w;
  w.us[0] = f2bf(a.x); w.us[1] = f2bf(a.y);
  w.us[2] = f2bf(a.z); w.us[3] = f2bf(a.w);
  w.us[4] = f2bf(b.x); w.us[5] = f2bf(b.y);
  w.us[6] = f2bf(b.z); w.us[7] = f2bf(b.w);
  return w.u4;
}

// Fragment-major layouts (per batch, stride 262144 u16 = 512 KB):
//   Kfrag[(t2*8+ks)*512 + hi*256 + l31*8 + j]          = K[t2*32+l31][ks*16+hi*8+j]
//   Vfrag[((t2*4+vb2)*2+th)*512 + hi*256 + l31*8 + j]  = V[t2*32+th*16+hi*8+j][vb2*32+l31]
#define BSTRIDE 262144

// W fragment layout for mfma32 (512 KB):
//   Wfrag[(ks*8+cf)*512 + hi*256 + l31*8 + j] = W[ks*16+hi*8+j][cf*32+l31]
//   (ks 0..63, cf 0..7 over [Wk|Wv] concat cols)

// ---------------------------------------------------------------------------
// Kernel 0: prep — [Wk|Wv] f32 -> bf16 mfma32-frag-major Wfrag.
// ---------------------------------------------------------------------------
__global__ void __launch_bounds__(256) prep_kernel(
    const float* __restrict__ Wk, const float* __restrict__ Wv,
    u16* __restrict__ Wfrag)
{
  int T = blockIdx.x * 256 + threadIdx.x;   // 0..32767
  int lane = T & 63;
  int fragid = T >> 6;                      // 0..511
  int ks = fragid >> 3, cf = fragid & 7;
  int l31 = lane & 31, hi = lane >> 5;
  int n = cf * 32 + l31;
  const float* src = (n < 128) ? (Wk + n) : (Wv + (n - 128));
  int k0 = ks * 16 + hi * 8;
  U128 w;
#pragma unroll
  for (int j = 0; j < 8; ++j) w.us[j] = f2bf(src[(size_t)(k0 + j) * KSZ]);
  *(uint4*)(Wfrag + (size_t)T * 8) = w.u4;
}

// ---------------------------------------------------------------------------
// Kernel 1: GEMM, structural clone of the (fast) attn kernel.
//   - mfma_f32_32x32x16 ONLY (attn's shape; R3..R12's mfma16 variants all
//     plateaued at 159 TF effective).
//   - W via plain 1KB frag-major loads (attn's K/V pattern), NO global_load_lds.
//   - X staged once into LDS (R12's verified 6.9TB/s pattern), ONE barrier.
//   - LDS-free epilogue: attn's verified pack+shfl_xor(32) frag assembly,
//     direct Kfrag/Vfrag stores from registers.
// Block 512 thr = 8 waves (2 row-halves x 4 col-quarters), 64 rows/block,
// grid 256 (1 block/CU, 128KB LDS). K-waves (cq<2): acc = mfma32(wf, xf)
// -> lane=row. V-waves: acc = mfma32(xf, wf) -> lane=col.
// ---------------------------------------------------------------------------
__global__ void __launch_bounds__(512, 1) gemm_kernel(
    const float* __restrict__ X, const u16* __restrict__ Wfrag,
    const float* __restrict__ bk, const float* __restrict__ bv,
    u16* __restrict__ Kfrag, u16* __restrict__ Vfrag)
{
  __shared__ u16 Xl[64 * 1024];   // 128 KB bf16, 16B-granule XOR swizzle

  const int tid  = threadIdx.x;
  const int lane = tid & 63;
  const int w    = tid >> 6;      // 0..7
  const int rh   = w >> 2;        // row half
  const int cq   = w & 3;         // col quarter
  const int l31  = lane & 31;
  const int hi   = lane >> 5;
  const int m0   = blockIdx.x * 64;

  // ---- Phase 1: stage X block (contiguous 32B/lane; proven pattern) ----
  {
    const int u  = tid & 127;     // 32B granule within row
    const int ro = tid >> 7;      // 0..3
#pragma unroll
    for (int h = 0; h < 4; ++h) {
      float4 t0[4], t1[4];
#pragma unroll
      for (int p = 0; p < 4; ++p) {
        int row = h * 16 + p * 4 + ro;
        const float4* xp = (const float4*)(X + (size_t)(m0 + row) * DMS + u * 8);
        t0[p] = xp[0]; t1[p] = xp[1];
      }
#pragma unroll
      for (int p = 0; p < 4; ++p) {
        int row = h * 16 + p * 4 + ro;
        *(uint4*)(Xl + row * 1024 + ((u * 8) ^ ((row & 7) << 3))) =
            pack8bf(t0[p], t1[p]);
      }
    }
  }
  __syncthreads();

  // ---- Phase 2: wave-autonomous K-loop (no barriers, no glds) ----
  f32x16 a0, a1;
#pragma unroll
  for (int i = 0; i < 16; ++i) { a0[i] = 0.f; a1[i] = 0.f; }

  const u16* wb = Wfrag + (size_t)(cq * 2) * 512 + hi * 256 + l31 * 8;
  const int xrow  = rh * 32 + l31;
  const int xbase = xrow * 1024;
  const int xswz  = (xrow & 7) << 3;

#pragma unroll 4
  for (int ks = 0; ks < 64; ++ks) {
    U128 xa;
    xa.u4 = *(const uint4*)(Xl + xbase + ((ks * 16 + hi * 8) ^ xswz));
    U128 w0, w1;
    const u16* wp = wb + (size_t)ks * 4096;
    w0.u4 = *(const uint4*)(wp);
    w1.u4 = *(const uint4*)(wp + 512);
    if (cq < 2) {
      a0 = mfma32(w0.b8, xa.b8, a0);
      a1 = mfma32(w1.b8, xa.b8, a1);
    } else {
      a0 = mfma32(xa.b8, w0.b8, a0);
      a1 = mfma32(xa.b8, w1.b8, a1);
    }
  }

  const int bb = m0 >> 11;                       // batch
  const int t2 = ((m0 & 2047) >> 5) + rh;        // 32-row tile within batch

  if (cq < 2) {
    // ---- K-waves: acc lane = row m (=l31), reg r -> n-off crow(r,hi) ----
#pragma unroll
    for (int r = 0; r < 16; ++r) {
      int crow = (r & 3) + 8 * (r >> 2) + 4 * hi;
      a0[r] += bk[cq * 64 + crow];
      a1[r] += bk[cq * 64 + 32 + crow];
    }
    u16* kb = Kfrag + (size_t)bb * BSTRIDE + (size_t)(t2 * 8) * 512 + l31 * 8;
#pragma unroll
    for (int ct = 0; ct < 2; ++ct) {
      const f32x16 a = ct ? a1 : a0;
      u32 c0 = packbf2(a[0],  a[1]),  c1 = packbf2(a[2],  a[3]);
      u32 c2 = packbf2(a[4],  a[5]),  c3 = packbf2(a[6],  a[7]);
      u32 c4 = packbf2(a[8],  a[9]),  c5 = packbf2(a[10], a[11]);
      u32 c6 = packbf2(a[12], a[13]), c7 = packbf2(a[14], a[15]);
      u32 d0 = __shfl_xor(c0, 32), d1 = __shfl_xor(c1, 32);
      u32 d2 = __shfl_xor(c2, 32), d3 = __shfl_xor(c3, 32);
      u32 d4 = __shfl_xor(c4, 32), d5 = __shfl_xor(c5, 32);
      u32 d6 = __shfl_xor(c6, 32), d7 = __shfl_xor(c7, 32);
      int ks2 = cq * 4 + ct * 2 + hi;            // hi=0: runs 0,8; hi=1: 16,24
      uint4 rA, rB;
      if (hi == 0) {
        rA = (uint4){c0, c1, d0, d1};            // n-off 0..7   (hi2=0)
        rB = (uint4){c2, c3, d2, d3};            // n-off 8..15  (hi2=1)
      } else {
        rA = (uint4){d4, d5, c4, c5};            // n-off 16..23 (hi2=0)
        rB = (uint4){d6, d7, c6, c7};            // n-off 24..31 (hi2=1)
      }
      *(uint4*)(kb + (size_t)ks2 * 512)       = rA;
      *(uint4*)(kb + (size_t)ks2 * 512 + 256) = rB;
    }
  } else {
    // ---- V-waves: acc lane = v-col, reg r -> m-off crow(r,hi) ----
    const int vq = cq - 2;
#pragma unroll
    for (int ct = 0; ct < 2; ++ct) {
      float bvv = bv[vq * 64 + ct * 32 + l31];
      if (ct) { for (int r = 0; r < 16; ++r) a1[r] += bvv; }
      else    { for (int r = 0; r < 16; ++r) a0[r] += bvv; }
    }
    u16* vb = Vfrag + (size_t)bb * BSTRIDE + l31 * 8;
#pragma unroll
    for (int ct = 0; ct < 2; ++ct) {
      const f32x16 a = ct ? a1 : a0;
      u32 c0 = packbf2(a[0],  a[1]),  c1 = packbf2(a[2],  a[3]);
      u32 c2 = packbf2(a[4],  a[5]),  c3 = packbf2(a[6],  a[7]);
      u32 c4 = packbf2(a[8],  a[9]),  c5 = packbf2(a[10], a[11]);
      u32 c6 = packbf2(a[12], a[13]), c7 = packbf2(a[14], a[15]);
      u32 d0 = __shfl_xor(c0, 32), d1 = __shfl_xor(c1, 32);
      u32 d2 = __shfl_xor(c2, 32), d3 = __shfl_xor(c3, 32);
      u32 d4 = __shfl_xor(c4, 32), d5 = __shfl_xor(c5, 32);
      u32 d6 = __shfl_xor(c6, 32), d7 = __shfl_xor(c7, 32);
      int vb2 = vq * 2 + ct;
      int th  = hi;                              // hi=0: m-runs 0,8; hi=1: 16,24
      uint4 rA, rB;
      if (hi == 0) {
        rA = (uint4){c0, c1, d0, d1};            // m-off 0..7   (hi3=0)
        rB = (uint4){c2, c3, d2, d3};            // m-off 8..15  (hi3=1)
      } else {
        rA = (uint4){d4, d5, c4, c5};            // m-off 16..23 (hi3=0)
        rB = (uint4){d6, d7, c6, c7};            // m-off 24..31 (hi3=1)
      }
      u16* dst = vb + (size_t)((t2 * 4 + vb2) * 2 + th) * 512;
      *(uint4*)(dst)       = rA;
      *(uint4*)(dst + 256) = rB;
    }
  }
}

// ---------------------------------------------------------------------------
// Kernel 2: causal flash attention + TAIL passthrough copy (unchanged).
// ---------------------------------------------------------------------------
__global__ void __launch_bounds__(256, 2) attn_kernel(
    const u16* __restrict__ Kfrag, const u16* __restrict__ Vfrag,
    const float* __restrict__ X, float* __restrict__ out)
{
  __shared__ float Om[4][128][33];
  __shared__ float Ml[4][2][32];
  __shared__ float Wm[4][32];
  __shared__ float Li[32];

  const int tid  = threadIdx.x;
  const int lane = tid & 63;
  const int w    = tid >> 6;
  const int l31  = lane & 31;
  const int hi   = lane >> 5;

  const int bi = blockIdx.x;
  const int b  = bi & 7;
  const int qt = (bi < 256) ? (63 - (bi >> 3)) : ((bi >> 3) - 32);
  const int q0 = qt * 32;

  const u16* Kb = Kfrag + (size_t)b * BSTRIDE;
  const u16* Vb = Vfrag + (size_t)b * BSTRIDE;
  const int loff = hi * 256 + l31 * 8;

  bf16x8 qf[8];
  {
    const u16* qp = Kb + (size_t)(qt * 8) * 512 + loff;
#pragma unroll
    for (int ks = 0; ks < 8; ++ks) {
      U128 u; u.u4 = *(const uint4*)(qp + ks * 512); qf[ks] = u.b8;
    }
  }

  f32x16 o[4];
#pragma unroll
  for (int vb2 = 0; vb2 < 4; ++vb2)
#pragma unroll
    for (int i = 0; i < 16; ++i) o[vb2][i] = 0.f;

  float mrun = -3.0e38f, lsum = 0.f;
  const float SC  = 0.08838834764831845f;
  const float L2E = 1.44269504088896341f;

  bf16x8 kf[8];
  {
    int ti0 = (w <= qt) ? w : 0;
    const u16* kp = Kb + (size_t)(ti0 * 8) * 512 + loff;
#pragma unroll
    for (int ks = 0; ks < 8; ++ks) {
      U128 u; u.u4 = *(const uint4*)(kp + ks * 512); kf[ks] = u.b8;
    }
  }

  for (int ti = w; ti <= qt; ti += 4) {
    bf16x8 vf[4][2];
    {
      const u16* vp = Vb + (size_t)(ti * 8) * 512 + loff;
#pragma unroll
      for (int vb2 = 0; vb2 < 4; ++vb2)
#pragma unroll
        for (int th = 0; th < 2; ++th) {
          U128 u; u.u4 = *(const uint4*)(vp + (vb2 * 2 + th) * 512);
          vf[vb2][th] = u.b8;
        }
    }
    f32x16 s;
#pragma unroll
    for (int i = 0; i < 16; ++i) s[i] = 0.f;
#pragma unroll
    for (int ks = 0; ks < 8; ++ks) s = mfma32(kf[ks], qf[ks], s);
    {
      int tin = (ti + 4 <= qt) ? ti + 4 : ti;
      const u16* kp = Kb + (size_t)(tin * 8) * 512 + loff;
#pragma unroll
      for (int ks = 0; ks < 8; ++ks) {
        U128 u; u.u4 = *(const uint4*)(kp + ks * 512); kf[ks] = u.b8;
      }
    }
    float sv[16];
#pragma unroll
    for (int r = 0; r < 16; ++r) sv[r] = s[r] * SC;
    if (ti == qt) {
#pragma unroll
      for (int r = 0; r < 16; ++r) {
        int toff = (r & 3) + 8 * (r >> 2) + 4 * hi;
        if (toff > l31) sv[r] = -3.0e38f;
      }
    }
    float mx = sv[0];
#pragma unroll
    for (int r = 1; r < 16; ++r) mx = fmaxf(mx, sv[r]);
    mx = fmaxf(mx, __shfl_xor(mx, 32));
    float p[16];
    float ps = 0.f;
    if (__all(mx - mrun <= 8.0f)) {
#pragma unroll
      for (int r = 0; r < 16; ++r) { p[r] = fexp2((sv[r] - mrun) * L2E); ps += p[r]; }
      ps += __shfl_xor(ps, 32);
      lsum += ps;
    } else {
      float mnew = fmaxf(mrun, mx);
      float al = fexp2((mrun - mnew) * L2E);
#pragma unroll
      for (int r = 0; r < 16; ++r) { p[r] = fexp2((sv[r] - mnew) * L2E); ps += p[r]; }
      ps += __shfl_xor(ps, 32);
      lsum = lsum * al + ps;
      mrun = mnew;
#pragma unroll
      for (int vb2 = 0; vb2 < 4; ++vb2)
#pragma unroll
        for (int i = 0; i < 16; ++i) o[vb2][i] *= al;
    }
    u32 c01 = packbf2(p[0],  p[1]);
    u32 c23 = packbf2(p[2],  p[3]);
    u32 c45 = packbf2(p[4],  p[5]);
    u32 c67 = packbf2(p[6],  p[7]);
    u32 c89 = packbf2(p[8],  p[9]);
    u32 cAB = packbf2(p[10], p[11]);
    u32 cCD = packbf2(p[12], p[13]);
    u32 cEF = packbf2(p[14], p[15]);
    u32 d01 = __shfl_xor(c01, 32);
    u32 d23 = __shfl_xor(c23, 32);
    u32 d45 = __shfl_xor(c45, 32);
    u32 d67 = __shfl_xor(c67, 32);
    u32 d89 = __shfl_xor(c89, 32);
    u32 dAB = __shfl_xor(cAB, 32);
    u32 dCD = __shfl_xor(cCD, 32);
    u32 dEF = __shfl_xor(cEF, 32);
    U128 pf1, pf2;
    pf1.u[0] = hi ? d45 : c01;
    pf1.u[1] = hi ? d67 : c23;
    pf1.u[2] = hi ? c45 : d01;
    pf1.u[3] = hi ? c67 : d23;
    pf2.u[0] = hi ? dCD : c89;
    pf2.u[1] = hi ? dEF : cAB;
    pf2.u[2] = hi ? cCD : d89;
    pf2.u[3] = hi ? cEF : dAB;
#pragma unroll
    for (int vb2 = 0; vb2 < 4; ++vb2) {
      o[vb2] = mfma32(vf[vb2][0], pf1.b8, o[vb2]);
      o[vb2] = mfma32(vf[vb2][1], pf2.b8, o[vb2]);
    }
  }

#pragma unroll
  for (int vb2 = 0; vb2 < 4; ++vb2)
#pragma unroll
    for (int r = 0; r < 16; ++r) {
      int v = vb2 * 32 + (r & 3) + 8 * (r >> 2) + 4 * hi;
      Om[w][v][l31] = o[vb2][r];
    }
  if (lane < 32) {
    Ml[w][0][l31] = mrun;
    Ml[w][1][l31] = lsum;
  }
  __syncthreads();

  if (tid < 32) {
    float m0 = Ml[0][0][tid], m1 = Ml[1][0][tid];
    float m2 = Ml[2][0][tid], m3 = Ml[3][0][tid];
    float M  = fmaxf(fmaxf(m0, m1), fmaxf(m2, m3));
    float w0 = fexp2((m0 - M) * L2E), w1 = fexp2((m1 - M) * L2E);
    float w2 = fexp2((m2 - M) * L2E), w3 = fexp2((m3 - M) * L2E);
    float L  = Ml[0][1][tid] * w0 + Ml[1][1][tid] * w1 +
               Ml[2][1][tid] * w2 + Ml[3][1][tid] * w3;
    Wm[0][tid] = w0; Wm[1][tid] = w1; Wm[2][tid] = w2; Wm[3][tid] = w3;
    Li[tid] = 1.f / L;
  }
  __syncthreads();

  {
    const int q = tid >> 3;
    const int vbase = (tid & 7) * 16;
    float wq0 = Wm[0][q], wq1 = Wm[1][q], wq2 = Wm[2][q], wq3 = Wm[3][q];
    float li = Li[q];
    float* orow = out + (size_t)(b * SEQ + q0 + q) * OD + 1024 + vbase;
#pragma unroll
    for (int i = 0; i < 16; i += 4) {
      float4 res;
      res.x = (Om[0][vbase + i + 0][q] * wq0 + Om[1][vbase + i + 0][q] * wq1 +
               Om[2][vbase + i + 0][q] * wq2 + Om[3][vbase + i + 0][q] * wq3) * li;
      res.y = (Om[0][vbase + i + 1][q] * wq0 + Om[1][vbase + i + 1][q] * wq1 +
               Om[2][vbase + i + 1][q] * wq2 + Om[3][vbase + i + 1][q] * wq3) * li;
      res.z = (Om[0][vbase + i + 2][q] * wq0 + Om[1][vbase + i + 2][q] * wq1 +
               Om[2][vbase + i + 2][q] * wq2 + Om[3][vbase + i + 2][q] * wq3) * li;
      res.w = (Om[0][vbase + i + 3][q] * wq0 + Om[1][vbase + i + 3][q] * wq1 +
               Om[2][vbase + i + 3][q] * wq2 + Om[3][vbase + i + 3][q] * wq3) * li;
      *(float4*)(orow + i) = res;
    }
  }

  // ---- TAIL passthrough copy ----
  {
#pragma unroll
    for (int r0 = 0; r0 < 32; r0 += 8) {
      float4 t[8];
#pragma unroll
      for (int j = 0; j < 8; ++j)
        t[j] = *((const float4*)(X + (size_t)(b * SEQ + q0 + r0 + j) * DMS) + tid);
#pragma unroll
      for (int j = 0; j < 8; ++j)
        *((float4*)(out + (size_t)(b * SEQ + q0 + r0 + j) * OD) + tid) = t[j];
    }
  }
}

extern "C" void kernel_launch(void* const* d_in, const int* in_sizes, int n_in,
                              void* d_out, int out_size, void* d_ws, size_t ws_size,
                              hipStream_t stream)
{
  const float* X  = (const float*)d_in[0];
  const float* Wk = (const float*)d_in[1];
  const float* bk = (const float*)d_in[2];
  const float* Wv = (const float*)d_in[3];
  const float* bv = (const float*)d_in[4];
  float* out = (float*)d_out;

  u16* Kfrag = (u16*)d_ws;                                 // 4 MB
  u16* Vfrag = Kfrag + (size_t)BATCH * BSTRIDE;            // 4 MB
  u16* Wfrag = Vfrag + (size_t)BATCH * BSTRIDE;            // 512 KB

  prep_kernel<<<dim3(128), dim3(256), 0, stream>>>(Wk, Wv, Wfrag);
  gemm_kernel<<<dim3(256), dim3(512), 0, stream>>>(X, Wfrag, bk, bv, Kfrag, Vfrag);
  attn_kernel<<<dim3(512), dim3(256), 0, stream>>>(Kfrag, Vfrag, X, out);
}